// Round 7
// baseline (414.262 us; speedup 1.0000x reference)
//
#include <hip/hip_runtime.h>
#include <math.h>

#define BATCH 2048
#define NN 64
#define FEAT 40
#define M 10
#define NWAVE 4
#define BLOCK 256
#define KS 65      // Kp row stride (floats): stride-65 -> conflict-free col access
#define XS 44      // xn row stride (floats): 176 B, 16B-aligned for float4

__device__ __forceinline__ float rl(float v, int l) {   // readlane, runtime l ok
    return __int_as_float(__builtin_amdgcn_readlane(__float_as_int(v), l));
}
__device__ __forceinline__ float wsum(float v) {
#pragma unroll
    for (int o = 32; o >= 1; o >>= 1) v += __shfl_xor(v, o, 64);
    return v;
}

// One 256-thread block (4 waves) per batch element. Matrix lives in LDS with
// ROLLED loops: total code ~500 instr (R6's register-array design forced a
// ~120KB unrolled stream + AGPR copy tax). LDL^T factorization, triangle-only
// Schur (block stays symmetric -> col k == row k), 1 barrier per k.
// Models sharing (ls,eps) share one factorization (group while-loop; executes
// once for the uniform real inputs). waves_per_eu(4,5): VGPR budget 102-128,
// enough for xcol[40]+working set; occupancy is LDS-bound at 5 blocks/CU.
__global__ __launch_bounds__(BLOCK)
__attribute__((amdgpu_waves_per_eu(4, 5)))
void muygps_kernel(
    const float* __restrict__ x,      // (20000, 40)
    const float* __restrict__ ls,     // (10,)
    const float* __restrict__ epsv,   // (10,)
    const int*   __restrict__ bidx,   // (2048,)
    const int*   __restrict__ nidx,   // (2048, 64)
    const float* __restrict__ tgt,    // (2048, 64, 10)
    float* __restrict__ out)          // pred(2048,10) | var(2048,10) | sigma(10)
{
    __shared__ float xn[NN * XS];     // neighbor features, row-major padded
    __shared__ float xb[FEAT];        // batch-point features
    __shared__ float Kp[NN * KS];     // kernel matrix -> scaled L^T (upper)
    __shared__ float Kc[NN];          // crosswise kernel vector
    __shared__ float rv[NN];          // 1/D[k]
    __shared__ float zs[(M + 1) * NN];// solved vectors: [0]=Kc, [m+1]=y_m

    const int b    = blockIdx.x;
    const int tid  = threadIdx.x;
    const int w    = tid >> 6;        // wave 0..3
    const int lane = tid & 63;

    // ---- stage xn, xb (float4, coalesced) ----
    for (int i4 = tid; i4 < NN * (FEAT / 4); i4 += BLOCK) {
        const int n = i4 / (FEAT / 4), q = i4 % (FEAT / 4);
        const float4 v = *(const float4*)(x + (long)nidx[b * NN + n] * FEAT + q * 4);
        *(float4*)(&xn[n * XS + q * 4]) = v;
    }
    if (tid < FEAT / 4)
        *(float4*)(&xb[tid * 4]) = *(const float4*)(x + (long)bidx[b] * FEAT + tid * 4);
    __syncthreads();

    // lane's own neighbor features in registers (reused all phases)
    float xcol[FEAT];
#pragma unroll
    for (int q = 0; q < FEAT / 4; ++q) {
        const float4 v = *(const float4*)(&xn[lane * XS + q * 4]);
        xcol[4*q] = v.x; xcol[4*q+1] = v.y; xcol[4*q+2] = v.z; xcol[4*q+3] = v.w;
    }

    unsigned done = 0;
    const unsigned all = (1u << M) - 1u;
    while (true) {
        const int   lead = __ffs(~done) - 1;        // block-uniform
        const float lls  = ls[lead];
        const float lep  = epsv[lead];
        const float il   = -1.0f / lls;

        // ---- Phase A: Kp rows (wave w: rows 16w..16w+15); Kc by wave 0 ----
        for (int it = 0; it < 16; ++it) {
            const int i = (w << 4) + it;
            const float* rp = &xn[i * XS];          // broadcast reads
            float d2 = 0.f;
#pragma unroll
            for (int f = 0; f < FEAT; ++f) {
                const float d = rp[f] - xcol[f];    // exact 0 on diag/duplicates
                d2 = fmaf(d, d, d2);
            }
            float v = __expf(sqrtf(d2) * il);
            if (lane == i) v += lep;
            Kp[i * KS + lane] = v;
        }
        if (w == 0) {
            float d2 = 0.f;
#pragma unroll
            for (int f = 0; f < FEAT; ++f) {
                const float d = xb[f] - xcol[f];
                d2 = fmaf(d, d, d2);
            }
            Kc[lane] = __expf(sqrtf(d2) * il);
        }
        __syncthreads();

        // ---- Phase B: LDL^T, triangle-only Schur, 1 barrier per k ----
        for (int k = 0; k < NN; ++k) {
            const float akk  = Kp[k * KS + k];                 // broadcast
            const float rk   = __builtin_amdgcn_rcpf(akk);
            if (tid == 0) rv[k] = rk;
            const float colv = Kp[k * KS + lane];              // row k == col k
            for (int i = k + 1 + w; i < NN; i += NWAVE) {      // rows striped
                const float lik = Kp[k * KS + i] * rk;         // broadcast
                if (lane >= i) {                               // upper triangle only
                    const int idx = i * KS + lane;
                    Kp[idx] = fmaf(-lik, colv, Kp[idx]);
                }
            }
            __syncthreads();
        }

        // ---- post-pass: upper -> L^T scaled (L[j][i]=A[i][j]*rv[i]); rest 0 ----
        for (int idx = tid; idx < NN * NN; idx += BLOCK) {
            const int i = idx >> 6, j = idx & 63;              // i uniform in-wave
            float v = 0.f;
            if (j > i) v = Kp[i * KS + j] * rv[i];
            Kp[i * KS + j] = v;
        }
        __syncthreads();

        // ---- Phase C: 3 fused forward solves per wave (unit-L) ----
        {
            const int r0 = w, r1 = w + 4, r2 = w + 8;
            // uniform-per-wave activity: r=0 -> Kc; r-1 must be undone group member
            auto act = [&](int r) -> bool {
                if (r == 0) return true;
                if (r > M) return false;
                const int m2 = r - 1;
                return !(done & (1u << m2)) && ls[m2] == lls && epsv[m2] == lep;
            };
            const bool a0 = act(r0), a1 = act(r1), a2 = act(r2);
            const long yb = ((long)b * NN + lane) * M;
            float z0 = a0 ? (r0 == 0 ? Kc[lane] : tgt[yb + r0 - 1]) : 0.f;
            float z1 = a1 ? tgt[yb + r1 - 1] : 0.f;
            float z2 = a2 ? tgt[yb + r2 - 1] : 0.f;
            for (int k = 0; k < NN - 1; ++k) {
                const float l0 = Kp[k * KS + lane];  // L[lane][k] (0 for lane<=k)
                z0 = fmaf(-l0, rl(z0, k), z0);
                z1 = fmaf(-l0, rl(z1, k), z1);
                z2 = fmaf(-l0, rl(z2, k), z2);
            }
            if (a0) zs[r0 * NN + lane] = z0;
            if (a1) zs[r1 * NN + lane] = z1;
            if (a2) zs[r2 * NN + lane] = z2;
        }
        __syncthreads();

        // ---- dots & writes (models striped over waves) ----
        {
            const float zc  = zs[lane];            // z_Kc
            const float rvl = rv[lane];
            const float quad = wsum(zc * zc * rvl);
            for (int m2 = w; m2 < M; m2 += NWAVE) {
                if (!(done & (1u << m2)) && ls[m2] == lls && epsv[m2] == lep) {
                    const float zm = zs[(m2 + 1) * NN + lane];
                    const float pm = wsum(zc * zm * rvl);
                    const float sm = wsum(zm * zm * rvl);
                    if (lane == 0) {
                        out[b * M + m2] = pm;
                        out[BATCH * M + b * M + m2] = 1.0f - quad;
                        atomicAdd(&out[2 * BATCH * M + m2],
                                  sm * (1.0f / (float)(BATCH * NN)));
                    }
                }
            }
        }

        // uniform done-update across ALL threads (keeps while-loop convergent)
#pragma unroll
        for (int m2 = 0; m2 < M; ++m2)
            if (ls[m2] == lls && epsv[m2] == lep) done |= 1u << m2;
        if (done == all) break;
        __syncthreads();   // protect Kp/rv/zs reuse across group iterations
    }
}

extern "C" void kernel_launch(void* const* d_in, const int* in_sizes, int n_in,
                              void* d_out, int out_size, void* d_ws, size_t ws_size,
                              hipStream_t stream) {
    const float* x   = (const float*)d_in[0];
    const float* lsp = (const float*)d_in[1];
    const float* ep  = (const float*)d_in[2];
    const int*   bi  = (const int*)d_in[3];
    const int*   ni  = (const int*)d_in[4];
    const float* tg  = (const float*)d_in[5];
    float* out = (float*)d_out;

    // sigma_sq region accumulated via atomics; d_out is poisoned each launch
    hipMemsetAsync(out + 2 * BATCH * M, 0, M * sizeof(float), stream);
    muygps_kernel<<<BATCH, BLOCK, 0, stream>>>(x, lsp, ep, bi, ni, tg, out);
}